// Round 16
// baseline (147.081 us; speedup 1.0000x reference)
//
#include <hip/hip_runtime.h>
#include <math.h>

#define B_  8
#define C_  64
#define H_  128
#define W_  128
#define KK_ 9
#define CO_ 64
#define HW_ (H_*W_)
#define CK_ 576

typedef _Float16 f16x8 __attribute__((ext_vector_type(8)));
typedef _Float16 h2    __attribute__((ext_vector_type(2)));
typedef __attribute__((ext_vector_type(4))) float f32x4;

__device__ inline unsigned pkrtz(float a, float b){
    auto v = __builtin_amdgcn_cvt_pkrtz(a, b);   // __fp16x2 on this toolchain
    union{decltype(v) h; unsigned u;} c; c.h = v; return c.u;
}
__device__ inline h2 u2h(unsigned u){ union{unsigned x; h2 h;} c; c.x = u; return c.h; }
__device__ inline unsigned h2u(h2 v){ union{h2 h; unsigned u;} c; c.h = v; return c.u; }
__device__ inline unsigned short f2h(float f){
    _Float16 h = (_Float16)f;
    union{_Float16 h; unsigned short s;} c; c.h = h; return c.s;
}
// broadcast lo/hi f16 of a dword into both halves (1 v_perm_b32 each)
__device__ inline h2 bcast_lo(unsigned u){ return u2h(__builtin_amdgcn_perm(u, u, 0x01000100)); }
__device__ inline h2 bcast_hi(unsigned u){ return u2h(__builtin_amdgcn_perm(u, u, 0x03020302)); }

// spin-wait on an LDS counter reaching 2; fence stops ds_read hoisting above
__device__ inline void lds_wait2(const volatile int* p){
    while (*p < 2) __builtin_amdgcn_s_sleep(2);
    asm volatile("" ::: "memory");
}
// signal: drain own LDS ops, then one atomicAdd per wave
__device__ inline void lds_signal(int* p, int lane){
    asm volatile("s_waitcnt lgkmcnt(0)" ::: "memory");
    if (lane == 0) atomicAdd(p, 1);
}

// ---- transpose_prep: fused x NCHW->NHWC f16 transpose + weight repack ----
__global__ __launch_bounds__(256) void transpose_prep(
    const float* __restrict__ x, unsigned short* __restrict__ xt,
    const float* __restrict__ w_dcn, const float* __restrict__ w_off,
    unsigned short* __restrict__ w_bf, unsigned short* __restrict__ wA)
{
    __shared__ unsigned tb[64 * 33];          // [pix][ch-pair], stride 33
    if (blockIdx.x >= B_ * 256) {             // weight-repack tail blocks
        int i = (blockIdx.x - B_ * 256) * 256 + threadIdx.x;
        if (i < 64 * CK_) {
            int o = i / CK_, r = i % CK_;
            int tap = r >> 6, c = r & 63;
            w_bf[i] = f2h(w_dcn[o * CK_ + c * 9 + tap]);
        } else {
            int j = i - 64 * CK_;             // 0 .. 32*576-1
            int o = j / CK_, r = j % CK_;
            int tap = r >> 6, c = r & 63;
            float v = (o < 27) ? w_off[o * CK_ + c * 9 + tap] : 0.f;
            wA[j] = f2h(v);
        }
        return;
    }
    int b = blockIdx.x >> 8;
    int pixbase = (blockIdx.x & 255) * 64;
    int t = threadIdx.x;
    #pragma unroll
    for (int i = 0; i < 2; ++i) {
        int idx = i * 256 + t;                // 0..511
        int cp = idx >> 4;                    // ch-pair 0..31
        int p4 = (idx & 15) * 4;              // pix 0..60 step 4
        const float* r0 = x + ((size_t)(b * C_) + 2 * cp    ) * HW_ + pixbase + p4;
        const float* r1 = x + ((size_t)(b * C_) + 2 * cp + 1) * HW_ + pixbase + p4;
        float4 f0 = *(const float4*)r0;
        float4 f1 = *(const float4*)r1;
        tb[(p4 + 0) * 33 + cp] = pkrtz(f0.x, f1.x);
        tb[(p4 + 1) * 33 + cp] = pkrtz(f0.y, f1.y);
        tb[(p4 + 2) * 33 + cp] = pkrtz(f0.z, f1.z);
        tb[(p4 + 3) * 33 + cp] = pkrtz(f0.w, f1.w);
    }
    __syncthreads();
    unsigned* xo = (unsigned*)xt + ((size_t)b * HW_ + pixbase) * 32;
    #pragma unroll
    for (int i = 0; i < 2; ++i) {
        int idx = i * 256 + t;
        int pix = idx >> 3, j = idx & 7;
        uint4 v;
        v.x = tb[pix * 33 + j * 4 + 0];
        v.y = tb[pix * 33 + j * 4 + 1];
        v.z = tb[pix * 33 + j * 4 + 2];
        v.w = tb[pix * 33 + j * 4 + 3];
        *(uint4*)(xo + pix * 32 + j * 4) = v;   // contiguous 1KB per wave-instr
    }
}

// ==== ROUND 16: dcn19 — producer/consumer WAVE SPECIALIZATION ==============
// Counters show no pipe >25%; every intra-wave pipeline attempt was
// compiler-collapsed; barriers quiesce all waves 8x/block. The one untried
// guide-endorsed pattern: wave specialization (no barriers in Phase B).
// Waves 0-1 = producers (gather+blend 9 taps into a 3-deep 9.2KB tap-buffer
// ring); waves 2-3 = consumers (each owns 32 out-channels, 16 MFMAs/tap).
// Sync: LDS counters pflag[9]/cflag[9]; producer of tap t waits
// cflag[t-3]==2, consumer waits pflag[t]==2. Monotone 3-buffer ring between
// co-resident waves -> deadlock-free. Per-sp blend math and per-acc MFMA
// (tap,half)-ascending k-order unchanged -> bit-exact.
// Pre-commit: dur<=60 -> specialization real; dur>=67 -> null, restore dcn15.

#define PXB 144                               // bytes per staged halo pixel
#define ROWB (66 * PXB)                       // 9504 B per staged row
#define SSTRB 144                             // tap-buffer row stride bytes
#define SBUF (64 * SSTRB)                     // 9216 B per tap buffer (x3 ring)

__global__ __launch_bounds__(256, 4) void dcn19(
    const unsigned short* __restrict__ xt,    // f16 NHWC
    const unsigned short* __restrict__ wA,    // offset-conv weights [32][576] f16
    const float* __restrict__ b_off,
    const unsigned short* __restrict__ w_bf,  // dcn weights [64][576] f16
    float* __restrict__ out)
{
    __shared__ __align__(16) unsigned char xrow[3 * ROWB];  // 28512 B (>= 3*SBUF)
    __shared__ uint2 scr_w[576];              // 4608 B, live through Phase B
    __shared__ int   scr_o[576];              // 2304 B
    __shared__ int   pflag[9];                // produced count per tap
    __shared__ int   cflag[9];                // consumed count per tap
    float* om = (float*)xrow;                 // alias after Phase A (barrier)
    unsigned char* sS = xrow;                 // alias in Phase B: 3-deep ring

    int tile = blockIdx.x;
    int b  = tile >> 8;
    int p0 = (tile & 255) * 64;
    int y  = p0 >> 7;
    int x0 = p0 & 127;
    int t  = threadIdx.x;
    int lane = t & 63, w = t >> 6;
    int m = lane & 15, q = lane >> 4;

    const unsigned short* xbr = xt + (size_t)(b * HW_) * 64;

    // ---- stage halo: rows y-1..y+1, cols x0-1..x0+64, zeros out of range ---
    for (int i = t; i < 3 * 66 * 8; i += 256) {
        int r = i / 528;                      // 0..2
        int rem = i - r * 528;
        int c = rem >> 3;                     // 0..65
        int g = rem & 7;                      // 16B chunk within pixel
        int yy = y - 1 + r;
        int xx = x0 - 1 + c;
        uint4 v = {0, 0, 0, 0};
        if (yy >= 0 && yy < H_ && xx >= 0 && xx < W_)
            v = *(const uint4*)(xbr + ((size_t)yy * W_ + xx) * 64 + g * 8);
        *(uint4*)(xrow + r * ROWB + c * PXB + g * 16) = v;
    }
    __syncthreads();

    // ---- Phase A: offset conv; B-operand from LDS halo (dcn15 verbatim) ----
    {
        int o0c = (w & 1) * 16;
        int pxh = (w >> 1) * 32;

        f32x4 accc[2] = {};
        #pragma unroll
        for (int ky = 0; ky < 3; ++ky) {
            #pragma unroll
            for (int kx = 0; kx < 3; ++kx) {
                int s2 = (ky * 3 + kx) * 2;
                f16x8 A0 = *(const f16x8*)(wA + (o0c + m) * CK_ + s2 * 32 + q * 8);
                f16x8 A1 = *(const f16x8*)(wA + (o0c + m) * CK_ + (s2 + 1) * 32 + q * 8);
                #pragma unroll
                for (int nt = 0; nt < 2; ++nt) {
                    int c = pxh + nt * 16 + m + kx;   // staged col (0..65)
                    const unsigned char* p = xrow + ky * ROWB + c * PXB + q * 16;
                    f16x8 b0 = *(const f16x8*)p;
                    f16x8 b1 = *(const f16x8*)(p + 64);
                    accc[nt] = __builtin_amdgcn_mfma_f32_16x16x32_f16(A0, b0, accc[nt], 0, 0, 0);
                    accc[nt] = __builtin_amdgcn_mfma_f32_16x16x32_f16(A1, b1, accc[nt], 0, 0, 0);
                }
            }
        }
        __syncthreads();      // halo dead; om about to overwrite the region
        #pragma unroll
        for (int nt = 0; nt < 2; ++nt) {
            #pragma unroll
            for (int r = 0; r < 4; ++r) {
                int j = o0c + q * 4 + r;
                if (j < 27)
                    om[j * 65 + pxh + nt * 16 + m] = accc[nt][r] + b_off[j];
            }
        }
    }
    __syncthreads();

    // ---- Phase 0: offsets -> 4xf16 weights + packed offsets (LDS scr) ------
    for (int i = t; i < 576; i += 256) {
        int k = i >> 6, sp = i & 63;
        float dy = om[(2 * k)     * 65 + sp];
        float dx = om[(2 * k + 1) * 65 + sp];
        float mk = 1.f / (1.f + __expf(-om[(18 + k) * 65 + sp]));
        float py = dy + (float)(y - 1 + k / 3);
        float px = dx + (float)(x0 + sp - 1 + k % 3);
        float fy = floorf(py), fx = floorf(px);
        int iy = (int)fy, ix = (int)fx;
        float ay = py - fy, ax = px - fx;
        float wy0 = (iy >= 0  && iy < H_)     ? (1.f - ay) : 0.f;
        float wy1 = (iy >= -1 && iy < H_ - 1) ? ay         : 0.f;
        float wx0 = (ix >= 0  && ix < W_)     ? (1.f - ax) : 0.f;
        float wx1 = (ix >= -1 && ix < W_ - 1) ? ax         : 0.f;
        int iy0 = min(max(iy, 0), H_ - 1);
        int iy1 = min(max(iy + 1, 0), H_ - 1);
        int ix0 = min(max(ix, 0), W_ - 1);
        int ix1 = min(max(ix + 1, 0), W_ - 1);
        float w00 = wy0*wx0*mk, w01 = wy0*wx1*mk, w10 = wy1*wx0*mk, w11 = wy1*wx1*mk;
        uint2 wv;
        wv.x = pkrtz(w00, w01);               // lo=w00 hi=w01
        wv.y = pkrtz(w10, w11);               // lo=w10 hi=w11
        scr_w[i] = wv;
        int off00 = (iy0 * W_ + ix0) * 128;   // bytes (64ch * 2B f16)
        scr_o[i] = off00 | ((ix1 != ix0) << 22) | ((iy1 != iy0) << 23);
    }
    if (t < 9) { pflag[t] = 0; cflag[t] = 0; }
    __syncthreads();        // scr+flags ready; om region (sS ring) now free
                            // LAST barrier in the kernel.

    // ---- Phase B: barrier-free producer/consumer wave specialization -------
    int cq = lane & 7;      // channel oct (8 ch = 16B)
    int g  = lane >> 3;     // 0..7
    const unsigned char* xb = (const unsigned char*)xbr;

    if (w < 2) {
        // ============ PRODUCER waves 0-1: gather+blend 9 taps ==============
        #pragma unroll
        for (int t9 = 0; t9 < 9; ++t9) {
            if (t9 >= 3) lds_wait2(&cflag[t9 - 3]);      // ring slot free
            unsigned char* sb = sS + (t9 % 3) * SBUF;
            #pragma unroll
            for (int u = 0; u < 4; ++u) {
                int sp = w * 32 + g * 4 + u;             // this lane's pixel
                int P  = t9 * 64 + sp;
                uint2 wv = scr_w[P];
                int   oo = scr_o[P];
                const unsigned char* a0 = xb + (oo & 0x3FFFFF) + cq * 16;
                int dxb = (oo >> 15) & 128;
                int dyb = (oo >> 9)  & 16384;
                uint4 a00 = *(const uint4*)(a0);
                uint4 a01 = *(const uint4*)(a0 + dxb);
                uint4 a10 = *(const uint4*)(a0 + dyb);
                uint4 a11 = *(const uint4*)(a0 + dyb + dxb);
                h2 w00 = bcast_lo(wv.x), w01 = bcast_hi(wv.x);
                h2 w10 = bcast_lo(wv.y), w11 = bcast_hi(wv.y);
                uint4 o4; h2 r;
                r = w00*u2h(a00.x) + w01*u2h(a01.x) + w10*u2h(a10.x) + w11*u2h(a11.x); o4.x = h2u(r);
                r = w00*u2h(a00.y) + w01*u2h(a01.y) + w10*u2h(a10.y) + w11*u2h(a11.y); o4.y = h2u(r);
                r = w00*u2h(a00.z) + w01*u2h(a01.z) + w10*u2h(a10.z) + w11*u2h(a11.z); o4.z = h2u(r);
                r = w00*u2h(a00.w) + w01*u2h(a01.w) + w10*u2h(a10.w) + w11*u2h(a11.w); o4.w = h2u(r);
                *(uint4*)&sb[sp * SSTRB + cq * 16] = o4;
            }
            lds_signal(&pflag[t9], lane);                // tap t9 published
        }
        return;   // producers done; no epilogue
    }

    // ============ CONSUMER waves 2-3: GEMM from the ring ====================
    int o0c2 = (w - 2) * 32;                  // this wave's 32 out-channels
    f32x4 acc2[2][4] = {};                    // [jo][nt], all indices static

    #pragma unroll
    for (int t9 = 0; t9 < 9; ++t9) {
        // Af loads issued BEFORE the wait -> latency hides under the poll
        const unsigned short* wb = w_bf + (o0c2 + m) * CK_ + (2 * t9) * 32 + q * 8;
        f16x8 Af00 = *(const f16x8*)(wb);                 // jo=0, h=0
        f16x8 Af01 = *(const f16x8*)(wb + 32);            // jo=0, h=1
        f16x8 Af10 = *(const f16x8*)(wb + 16 * CK_);      // jo=1, h=0
        f16x8 Af11 = *(const f16x8*)(wb + 16 * CK_ + 32); // jo=1, h=1

        lds_wait2(&pflag[t9]);                            // tap data ready
        const unsigned char* sb = sS + (t9 % 3) * SBUF;

        #pragma unroll
        for (int nt = 0; nt < 4; ++nt) {
            f16x8 bb0 = *(const f16x8*)&sb[(nt * 16 + m) * SSTRB + q * 16];
            acc2[0][nt] = __builtin_amdgcn_mfma_f32_16x16x32_f16(Af00, bb0, acc2[0][nt], 0, 0, 0);
            acc2[1][nt] = __builtin_amdgcn_mfma_f32_16x16x32_f16(Af10, bb0, acc2[1][nt], 0, 0, 0);
        }
        #pragma unroll
        for (int nt = 0; nt < 4; ++nt) {
            f16x8 bb1 = *(const f16x8*)&sb[(nt * 16 + m) * SSTRB + 64 + q * 16];
            acc2[0][nt] = __builtin_amdgcn_mfma_f32_16x16x32_f16(Af01, bb1, acc2[0][nt], 0, 0, 0);
            acc2[1][nt] = __builtin_amdgcn_mfma_f32_16x16x32_f16(Af11, bb1, acc2[1][nt], 0, 0, 0);
        }
        lds_signal(&cflag[t9], lane);                     // ring slot released
    }

    // Epilogue: col(px)=m, row(o)=q*4+reg; wave covers outs o0c2..o0c2+31
    #pragma unroll
    for (int jo = 0; jo < 2; ++jo) {
        #pragma unroll
        for (int nt = 0; nt < 4; ++nt) {
            #pragma unroll
            for (int r = 0; r < 4; ++r) {
                int o = o0c2 + jo * 16 + q * 4 + r;
                out[((size_t)(b * CO_ + o)) * HW_ + p0 + nt * 16 + m] = acc2[jo][nt][r];
            }
        }
    }
}

extern "C" void kernel_launch(void* const* d_in, const int* in_sizes, int n_in,
                              void* d_out, int out_size, void* d_ws, size_t ws_size,
                              hipStream_t stream)
{
    const float* x     = (const float*)d_in[0];
    const float* w_off = (const float*)d_in[1];
    const float* b_off = (const float*)d_in[2];
    const float* w_dcn = (const float*)d_in[3];
    float* out = (float*)d_out;

    unsigned short* xt   = (unsigned short*)d_ws;                // 16.8 MB
    unsigned short* w_bf = xt + (size_t)B_ * HW_ * 64;           // 73.7 KB
    unsigned short* wA   = w_bf + 64 * CK_;                      // 36.9 KB

    transpose_prep<<<B_ * 256 + 216, 256, 0, stream>>>(x, xt, w_dcn, w_off, w_bf, wA);
    dcn19<<<B_ * 256, 256, 0, stream>>>(xt, wA, b_off, w_bf, out);
}